// Round 1
// baseline (52.141 us; speedup 1.0000x reference)
//
#include <hip/hip_runtime.h>
#include <math.h>

#define B_    32
#define PPB   256
#define N_    (B_*PPB)     // 8192 proposals / padded slots
#define M_    128
#define LANG_ 256
#define H_    128
#define EPS_  1e-5f
#define COLS  32           // columns per MLP block

// ---------------------------------------------------------------------------
// Kernel A: per-proposal batch id, within-chunk stable rank, chunk histograms.
// One block per 256-proposal chunk.
// ---------------------------------------------------------------------------
__global__ __launch_bounds__(256) void k_map_a(
    const int* __restrict__ pidx, const int* __restrict__ poff,
    const int* __restrict__ boff, int* __restrict__ bid_g,
    int* __restrict__ wrank_g, int* __restrict__ hist_g,
    int* __restrict__ src_of_dest)
{
  __shared__ int sb[33];
  __shared__ int sbid[256];
  __shared__ int shist[32];
  const int tid = threadIdx.x;
  const int i = blockIdx.x * 256 + tid;
  if (tid < 33) sb[tid] = boff[tid];
  if (tid < 32) shist[tid] = 0;
  __syncthreads();
  const int off = poff[i];
  const int fp  = pidx[2 * off + 1];
  int cnt = 0;
  #pragma unroll
  for (int j = 0; j < 33; ++j) cnt += (sb[j] <= fp) ? 1 : 0;
  int bd = cnt - 1;
  bd = bd < 0 ? 0 : (bd > 31 ? 31 : bd);
  sbid[tid] = bd;
  bid_g[i] = bd;
  src_of_dest[i] = -1;          // init inverse map (N_ == B_*PPB)
  atomicAdd(&shist[bd], 1);
  __syncthreads();
  // stable rank within chunk (brute force over <=255 LDS words)
  int r = 0;
  for (int j = 0; j < tid; ++j) r += (sbid[j] == bd) ? 1 : 0;
  wrank_g[i] = r;
  if (tid < 32) hist_g[blockIdx.x * 32 + tid] = shist[tid];
}

// ---------------------------------------------------------------------------
// Kernel B: cross-chunk exclusive scan per bin, scatter inverse map, fold BN.
// Single block, 1024 threads.
// ---------------------------------------------------------------------------
__global__ __launch_bounds__(1024) void k_map_b(
    const int* __restrict__ bid_g, const int* __restrict__ wrank_g,
    const int* __restrict__ hist_g, int* __restrict__ src_of_dest,
    const float* __restrict__ g1, const float* __restrict__ be1,
    const float* __restrict__ rm1, const float* __restrict__ rv1,
    const float* __restrict__ g2, const float* __restrict__ be2,
    const float* __restrict__ rm2, const float* __restrict__ rv2,
    float* __restrict__ s1, float* __restrict__ t1,
    float* __restrict__ s2, float* __restrict__ t2)
{
  __shared__ int cb[32][32];   // cb[chunk][bin] = exclusive prefix of hist over chunks
  const int tid = threadIdx.x;
  if (tid < 32) {
    int run = 0;
    for (int c = 0; c < 32; ++c) { cb[c][tid] = run; run += hist_g[c * 32 + tid]; }
  } else if (tid >= 512 && tid < 640) {
    const int o = tid - 512;
    const float s = g1[o] / sqrtf(rv1[o] + EPS_);
    s1[o] = s; t1[o] = be1[o] - rm1[o] * s;
  } else if (tid >= 640 && tid < 768) {
    const int o = tid - 640;
    const float s = g2[o] / sqrtf(rv2[o] + EPS_);
    s2[o] = s; t2[o] = be2[o] - rm2[o] * s;
  }
  __syncthreads();
  #pragma unroll
  for (int k = 0; k < 8; ++k) {
    const int i = tid * 8 + k;
    const int bd = bid_g[i];
    const int rank = cb[i >> 8][bd] + wrank_g[i];
    if (rank < PPB) src_of_dest[bd * PPB + rank] = i;   // OOB updates dropped (matches .at.set)
  }
}

// ---------------------------------------------------------------------------
// Kernel C: langproj[b][o] = W_fuse[o,128:384] . lang_emb[b]
// ---------------------------------------------------------------------------
__global__ __launch_bounds__(128) void k_lang(
    const float* __restrict__ Wf, const float* __restrict__ lang,
    float* __restrict__ lp)
{
  const int b = blockIdx.x, o = threadIdx.x;
  float acc = 0.f;
  for (int l = 0; l < LANG_; l += 4) {
    const float4 w = *reinterpret_cast<const float4*>(Wf + o * 384 + 128 + l);
    const float4 e = *reinterpret_cast<const float4*>(lang + b * LANG_ + l);
    acc += w.x * e.x + w.y * e.y + w.z * e.z + w.w * e.w;
  }
  lp[b * H_ + o] = acc;
}

// ---------------------------------------------------------------------------
// Kernel D: fused MLP over 32 columns per block; 256 blocks (1/CU).
// LDS ping-pong [p][c] activation buffers; weights streamed from global.
// ---------------------------------------------------------------------------
__global__ __launch_bounds__(256) void k_mlp(
    const float* __restrict__ feats,
    const float* __restrict__ Wf, const float* __restrict__ bf,
    const float* __restrict__ W1, const float* __restrict__ b1,
    const float* __restrict__ W2, const float* __restrict__ b2,
    const float* __restrict__ W3, const float* __restrict__ b3,
    const int* __restrict__ src_of_dest, const float* __restrict__ lp,
    const float* __restrict__ s1, const float* __restrict__ t1,
    const float* __restrict__ s2, const float* __restrict__ t2,
    float* __restrict__ out)
{
  __shared__ float bufA[COLS][H_ + 4];
  __shared__ float bufB[COLS][H_ + 4];
  const int tid = threadIdx.x;
  const int q0 = blockIdx.x * COLS;
  const int b = q0 >> 8;          // COLS divides PPB -> whole block same batch

  // ---- stage gathered feats into bufA as [p][c]
  {
    const int r = tid >> 3, cj = tid & 7;
    const int srow = src_of_dest[q0 + r];
    #pragma unroll
    for (int pass = 0; pass < 4; ++pass) {
      const int c = pass * 32 + cj * 4;
      float4 v = make_float4(0.f, 0.f, 0.f, 0.f);
      if (srow >= 0) v = *reinterpret_cast<const float4*>(feats + (size_t)srow * M_ + c);
      *reinterpret_cast<float4*>(&bufA[r][c]) = v;
    }
  }
  __syncthreads();

  const int og = tid >> 4, pg = tid & 15;
  const int o0 = og * 8;

  // ---- layer 0: relu(Wf[:, :128] @ X + langproj + b_fuse), bufA -> bufB
  {
    float acc0[8], acc1[8];
    #pragma unroll
    for (int k = 0; k < 8; ++k) { acc0[k] = 0.f; acc1[k] = 0.f; }
    for (int c = 0; c < H_; c += 4) {
      const float4 xa = *reinterpret_cast<const float4*>(&bufA[pg][c]);
      const float4 xb = *reinterpret_cast<const float4*>(&bufA[pg + 16][c]);
      #pragma unroll
      for (int k = 0; k < 8; ++k) {
        const float4 w = *reinterpret_cast<const float4*>(Wf + (o0 + k) * 384 + c);
        acc0[k] += w.x * xa.x + w.y * xa.y + w.z * xa.z + w.w * xa.w;
        acc1[k] += w.x * xb.x + w.y * xb.y + w.z * xb.z + w.w * xb.w;
      }
    }
    #pragma unroll
    for (int k = 0; k < 8; ++k) {
      const int o = o0 + k;
      const float base = lp[b * H_ + o] + bf[o];
      bufB[pg][o]      = fmaxf(acc0[k] + base, 0.f);
      bufB[pg + 16][o] = fmaxf(acc1[k] + base, 0.f);
    }
  }
  __syncthreads();

  // ---- layer 1: BN1(relu(W1 @ h0 + b1)) = relu(z)*s1 + t1, bufB -> bufA
  {
    float acc0[8], acc1[8];
    #pragma unroll
    for (int k = 0; k < 8; ++k) { acc0[k] = 0.f; acc1[k] = 0.f; }
    for (int c = 0; c < H_; c += 4) {
      const float4 xa = *reinterpret_cast<const float4*>(&bufB[pg][c]);
      const float4 xb = *reinterpret_cast<const float4*>(&bufB[pg + 16][c]);
      #pragma unroll
      for (int k = 0; k < 8; ++k) {
        const float4 w = *reinterpret_cast<const float4*>(W1 + (o0 + k) * H_ + c);
        acc0[k] += w.x * xa.x + w.y * xa.y + w.z * xa.z + w.w * xa.w;
        acc1[k] += w.x * xb.x + w.y * xb.y + w.z * xb.z + w.w * xb.w;
      }
    }
    #pragma unroll
    for (int k = 0; k < 8; ++k) {
      const int o = o0 + k;
      const float bb = b1[o], ss = s1[o], tt = t1[o];
      bufA[pg][o]      = fmaxf(acc0[k] + bb, 0.f) * ss + tt;
      bufA[pg + 16][o] = fmaxf(acc1[k] + bb, 0.f) * ss + tt;
    }
  }
  __syncthreads();

  // ---- layer 2: BN2(relu(W2 @ h1 + b2)), bufA -> bufB
  {
    float acc0[8], acc1[8];
    #pragma unroll
    for (int k = 0; k < 8; ++k) { acc0[k] = 0.f; acc1[k] = 0.f; }
    for (int c = 0; c < H_; c += 4) {
      const float4 xa = *reinterpret_cast<const float4*>(&bufA[pg][c]);
      const float4 xb = *reinterpret_cast<const float4*>(&bufA[pg + 16][c]);
      #pragma unroll
      for (int k = 0; k < 8; ++k) {
        const float4 w = *reinterpret_cast<const float4*>(W2 + (o0 + k) * H_ + c);
        acc0[k] += w.x * xa.x + w.y * xa.y + w.z * xa.z + w.w * xa.w;
        acc1[k] += w.x * xb.x + w.y * xb.y + w.z * xb.z + w.w * xb.w;
      }
    }
    #pragma unroll
    for (int k = 0; k < 8; ++k) {
      const int o = o0 + k;
      const float bb = b2[o], ss = s2[o], tt = t2[o];
      bufB[pg][o]      = fmaxf(acc0[k] + bb, 0.f) * ss + tt;
      bufB[pg + 16][o] = fmaxf(acc1[k] + bb, 0.f) * ss + tt;
    }
  }
  __syncthreads();

  // ---- final: out[q] = W3 . h2[:,p] + b3 ; 8 lanes per column, shuffle reduce
  {
    const int col = tid >> 3, k = tid & 7;
    float p = 0.f;
    #pragma unroll
    for (int j = 0; j < 4; ++j) {
      const int c = k * 16 + j * 4;
      const float4 x = *reinterpret_cast<const float4*>(&bufB[col][c]);
      const float4 w = *reinterpret_cast<const float4*>(W3 + c);
      p += w.x * x.x + w.y * x.y + w.z * x.z + w.w * x.w;
    }
    p += __shfl_xor(p, 1);
    p += __shfl_xor(p, 2);
    p += __shfl_xor(p, 4);
    if (k == 0) out[q0 + col] = p + b3[0];
  }
}

// ---------------------------------------------------------------------------
extern "C" void kernel_launch(void* const* d_in, const int* in_sizes, int n_in,
                              void* d_out, int out_size, void* d_ws, size_t ws_size,
                              hipStream_t stream) {
  const float* feats = (const float*)d_in[0];
  const int*   pidx  = (const int*)d_in[1];
  const int*   poff  = (const int*)d_in[2];
  const int*   boff  = (const int*)d_in[3];
  const float* lang  = (const float*)d_in[4];
  const float* Wf    = (const float*)d_in[5];
  const float* bf    = (const float*)d_in[6];
  const float* W1    = (const float*)d_in[7];
  const float* b1    = (const float*)d_in[8];
  const float* g1    = (const float*)d_in[9];
  const float* be1   = (const float*)d_in[10];
  const float* rm1   = (const float*)d_in[11];
  const float* rv1   = (const float*)d_in[12];
  const float* W2    = (const float*)d_in[13];
  const float* b2    = (const float*)d_in[14];
  const float* g2    = (const float*)d_in[15];
  const float* be2   = (const float*)d_in[16];
  const float* rm2   = (const float*)d_in[17];
  const float* rv2   = (const float*)d_in[18];
  const float* W3    = (const float*)d_in[19];
  const float* b3    = (const float*)d_in[20];
  float* out = (float*)d_out;

  int* srcmap = (int*)d_ws;
  int* bidp   = srcmap + N_;
  int* wrank  = bidp + N_;
  int* hist   = wrank + N_;
  float* lp = (float*)(hist + 32 * 32);
  float* s1 = lp + B_ * H_;
  float* t1 = s1 + H_;
  float* s2 = t1 + H_;
  float* t2 = s2 + H_;

  hipLaunchKernelGGL(k_map_a, dim3(32), dim3(256), 0, stream,
                     pidx, poff, boff, bidp, wrank, hist, srcmap);
  hipLaunchKernelGGL(k_map_b, dim3(1), dim3(1024), 0, stream,
                     bidp, wrank, hist, srcmap,
                     g1, be1, rm1, rv1, g2, be2, rm2, rv2, s1, t1, s2, t2);
  hipLaunchKernelGGL(k_lang, dim3(B_), dim3(H_), 0, stream, Wf, lang, lp);
  hipLaunchKernelGGL(k_mlp, dim3(N_ / COLS), dim3(256), 0, stream,
                     feats, Wf, bf, W1, b1, W2, b2, W3, b3,
                     srcmap, lp, s1, t1, s2, t2, out);
}